// Round 14
// baseline (251.526 us; speedup 1.0000x reference)
//
#include <hip/hip_runtime.h>
#include <math.h>

// MultiHeadedAttention  B=2, S=2048, D=1024, H=16, DH=64 (fp32 in/out)
// R24 (baseline = R23, total 246.9us best; conflicts=0 kept): attn span
// rescheduled: QK0 -> QK1 -> SM0 (in QK1's MFMA shadow) -> PV0 with SM1
// interleaved 1:1 (8 MFMA : 8 sm-chunks) -> PV1. Same math, same fp order;
// sm-split precedent m214 r283 (+5%). Everything else identical to R23.
// ws: Qbf@0 Kbf@8M Vt@16M mpk@32M Whi@33M ctxHi@41M ctxLo@49M Abf@57M

constexpr int Bc  = 2;
constexpr int Sc  = 2048;
constexpr int Dc  = 1024;
constexpr int Hc  = 16;
constexpr int DHc = 64;
constexpr int BSc = Bc * Sc;     // 4096

constexpr float LOG2E = 1.4426950408889634f;

typedef __bf16 bf16x8 __attribute__((ext_vector_type(8)));
typedef __bf16 bf16x4 __attribute__((ext_vector_type(4)));
typedef __bf16 bf16x2 __attribute__((ext_vector_type(2)));
typedef float  f32x4  __attribute__((ext_vector_type(4)));
typedef float  f32x16 __attribute__((ext_vector_type(16)));
typedef unsigned uint32x2 __attribute__((ext_vector_type(2)));
typedef unsigned uint32x4 __attribute__((ext_vector_type(4)));

#define GLDS16(gp, lp) __builtin_amdgcn_global_load_lds( \
    (const __attribute__((address_space(1))) void*)(gp), \
    (__attribute__((address_space(3))) void*)(lp), 16, 0, 0)

// ---------------------------------------------------------------------------
// prep: fused wsplit (blocks 0..4095) + acast (4096..10239) +
// mask_pack (10240..18431). No inter-part dependencies.
// ---------------------------------------------------------------------------
__global__ __launch_bounds__(256)
void prep(const float* __restrict__ W0, const float* __restrict__ W1,
          const float* __restrict__ W2, const float* __restrict__ W3,
          __bf16* __restrict__ Whi,
          const float* __restrict__ A0, const float* __restrict__ A1,
          const float* __restrict__ A2, __bf16* __restrict__ Abf,
          const int* __restrict__ mask, unsigned long long* __restrict__ mpk)
{
    const int bid = blockIdx.x;
    const int tid = threadIdx.x;

    if (bid < 4096) {
        const float* src[4] = {W0, W1, W2, W3};
        const int z  = bid >> 10;
        const int bx = bid & 1023;
        const size_t idx = ((size_t)bx * 256 + tid) * 4;
        const float4 v = *(const float4*)&src[z][idx];
        bf16x4 o;
        o[0] = (__bf16)v.x; o[1] = (__bf16)v.y;
        o[2] = (__bf16)v.z; o[3] = (__bf16)v.w;
        *(bf16x4*)&Whi[(size_t)z * Dc * Dc + idx] = o;
    } else if (bid < 10240) {
        const float* src[3] = {A0, A1, A2};
        const int lin = bid - 4096;
        const int z  = lin >> 11;
        const int bx = lin & 2047;
        const size_t idx = ((size_t)bx * 256 + tid) * 8;
        const float4 a = *(const float4*)&src[z][idx];
        const float4 b = *(const float4*)&src[z][idx + 4];
        bf16x8 o;
        o[0] = (__bf16)a.x; o[1] = (__bf16)a.y; o[2] = (__bf16)a.z; o[3] = (__bf16)a.w;
        o[4] = (__bf16)b.x; o[5] = (__bf16)b.y; o[6] = (__bf16)b.z; o[7] = (__bf16)b.w;
        *(bf16x8*)&Abf[(size_t)z * BSc * Dc + idx] = o;
    } else {
        const int bx   = bid - 10240;
        const int lane = tid & 63;
        const size_t waveBase = ((size_t)bx * 4 + (tid >> 6)) * 256;
        unsigned long long b0 = __ballot(mask[waveBase + lane]        != 0);
        unsigned long long b1 = __ballot(mask[waveBase + 64 + lane]   != 0);
        unsigned long long b2 = __ballot(mask[waveBase + 128 + lane]  != 0);
        unsigned long long b3 = __ballot(mask[waveBase + 192 + lane]  != 0);
        if (lane == 0) {
            unsigned long long* dst = mpk + (waveBase >> 6);
            dst[0] = b0; dst[1] = b1; dst[2] = b2; dst[3] = b3;
        }
    }
}

// ---------------------------------------------------------------------------
// Pure double-GLDS K-sweep, M-tile 128 (qkv).
// ---------------------------------------------------------------------------
template<int KD>
__device__ __forceinline__ void sweep128bb(const __bf16* __restrict__ A,
                                           const __bf16* __restrict__ Wh,
                                           char* AsB, char* WsB,
                                           int gm0, int gn0, f32x4 acc[4][4])
{
    const int tid  = threadIdx.x;
    const int w    = tid >> 6;
    const int lane = tid & 63;
    const int cc   = lane & 15;
    const int g    = lane >> 4;
    const int wm   = (w & 1) * 64;
    const int wn   = (w >> 1) * 64;

    int wrow[4], wchk[4];
#pragma unroll
    for (int r = 0; r < 4; ++r) {
        const int L = r * 256 + tid;
        wrow[r] = L >> 3;
        wchk[r] = (L & 7) ^ (wrow[r] & 7);
    }

#pragma unroll
    for (int r = 0; r < 4; ++r) {
        GLDS16(Wh + (size_t)(gn0 + wrow[r]) * KD + wchk[r] * 8,
               WsB + (r * 256 + tid) * 16);
        GLDS16(A + (size_t)(gm0 + wrow[r]) * KD + wchk[r] * 8,
               AsB + (r * 256 + tid) * 16);
    }

    for (int it = 0; it < KD / 64; ++it) {
        const char* As = AsB + (it & 1) * 16384;
        const char* Ws = WsB + (it & 1) * 16384;
        __syncthreads();

        if (it + 1 < KD / 64) {
            const int kn = (it + 1) * 64;
            char* Wn = WsB + ((it + 1) & 1) * 16384;
            char* An = AsB + ((it + 1) & 1) * 16384;
#pragma unroll
            for (int r = 0; r < 4; ++r) {
                GLDS16(Wh + (size_t)(gn0 + wrow[r]) * KD + kn + wchk[r] * 8,
                       Wn + (r * 256 + tid) * 16);
                GLDS16(A + (size_t)(gm0 + wrow[r]) * KD + kn + wchk[r] * 8,
                       An + (r * 256 + tid) * 16);
            }
        }

        __builtin_amdgcn_s_setprio(1);
#pragma unroll
        for (int kk = 0; kk < 2; ++kk) {
            const int cb4 = (kk * 4 + g) << 4;
            bf16x8 af[4], bfr[4];
#pragma unroll
            for (int mt = 0; mt < 4; ++mt) {
                const int row = wm + mt * 16 + cc;
                af[mt] = *(const bf16x8*)(As + row * 128 + (cb4 ^ ((row & 7) << 4)));
            }
#pragma unroll
            for (int nt = 0; nt < 4; ++nt) {
                const int row = wn + nt * 16 + cc;
                bfr[nt] = *(const bf16x8*)(Ws + row * 128 + (cb4 ^ ((row & 7) << 4)));
            }
#pragma unroll
            for (int mt = 0; mt < 4; ++mt)
#pragma unroll
                for (int nt = 0; nt < 4; ++nt)
                    acc[mt][nt] = __builtin_amdgcn_mfma_f32_16x16x32_bf16(
                        af[mt], bfr[nt], acc[mt][nt], 0, 0, 0);
        }
        __builtin_amdgcn_s_setprio(0);
    }
}

// ---------------------------------------------------------------------------
// Pipelined hi/lo K-sweep, M64 (out projection).
// ---------------------------------------------------------------------------
__device__ __forceinline__ void sweep64p(const __bf16* __restrict__ Ahi,
                                         const __bf16* __restrict__ Alo,
                                         const __bf16* __restrict__ Wh,
                                         char* WsB, char* AhB, char* AlB,
                                         int gm0, int gn0, f32x4 acc[2][4])
{
    const int tid  = threadIdx.x;
    const int w    = tid >> 6;
    const int lane = tid & 63;
    const int cc   = lane & 15;
    const int g    = lane >> 4;
    const int wm   = (w & 1) * 32;
    const int wn   = (w >> 1) * 64;

    int wrow[4], wchk[4];
#pragma unroll
    for (int r = 0; r < 4; ++r) {
        const int L = r * 256 + tid;
        wrow[r] = L >> 3;
        wchk[r] = (L & 7) ^ (wrow[r] & 7);
    }
    int arow[2], achk[2];
#pragma unroll
    for (int r = 0; r < 2; ++r) {
        const int L = r * 256 + tid;
        arow[r] = L >> 3;
        achk[r] = (L & 7) ^ (arow[r] & 7);
    }

#pragma unroll
    for (int r = 0; r < 4; ++r)
        GLDS16(Wh + (size_t)(gn0 + wrow[r]) * Dc + wchk[r] * 8,
               WsB + (r * 256 + tid) * 16);
#pragma unroll
    for (int r = 0; r < 2; ++r) {
        GLDS16(Ahi + (size_t)(gm0 + arow[r]) * Dc + achk[r] * 8,
               AhB + (r * 256 + tid) * 16);
        GLDS16(Alo + (size_t)(gm0 + arow[r]) * Dc + achk[r] * 8,
               AlB + (r * 256 + tid) * 16);
    }

    for (int it = 0; it < Dc / 64; ++it) {
        const char* Ws = WsB + (it & 1) * 16384;
        const char* Ah = AhB + (it & 1) * 8192;
        const char* Al = AlB + (it & 1) * 8192;
        __syncthreads();

        if (it + 1 < Dc / 64) {
            const int kn = (it + 1) * 64;
            char* Wn = WsB + ((it + 1) & 1) * 16384;
            char* Hn = AhB + ((it + 1) & 1) * 8192;
            char* Ln = AlB + ((it + 1) & 1) * 8192;
#pragma unroll
            for (int r = 0; r < 4; ++r)
                GLDS16(Wh + (size_t)(gn0 + wrow[r]) * Dc + kn + wchk[r] * 8,
                       Wn + (r * 256 + tid) * 16);
#pragma unroll
            for (int r = 0; r < 2; ++r) {
                GLDS16(Ahi + (size_t)(gm0 + arow[r]) * Dc + kn + achk[r] * 8,
                       Hn + (r * 256 + tid) * 16);
                GLDS16(Alo + (size_t)(gm0 + arow[r]) * Dc + kn + achk[r] * 8,
                       Ln + (r * 256 + tid) * 16);
            }
        }

        __builtin_amdgcn_s_setprio(1);
#pragma unroll
        for (int kk = 0; kk < 2; ++kk) {
            const int cb4 = (kk * 4 + g) << 4;
            bf16x8 ahi[2], alo[2], bfr[4];
#pragma unroll
            for (int mt = 0; mt < 2; ++mt) {
                const int row = wm + mt * 16 + cc;
                const int off = row * 128 + (cb4 ^ ((row & 7) << 4));
                ahi[mt] = *(const bf16x8*)(Ah + off);
                alo[mt] = *(const bf16x8*)(Al + off);
            }
#pragma unroll
            for (int nt = 0; nt < 4; ++nt) {
                const int row = wn + nt * 16 + cc;
                bfr[nt] = *(const bf16x8*)(Ws + row * 128 + (cb4 ^ ((row & 7) << 4)));
            }
#pragma unroll
            for (int mt = 0; mt < 2; ++mt)
#pragma unroll
                for (int nt = 0; nt < 4; ++nt) {
                    acc[mt][nt] = __builtin_amdgcn_mfma_f32_16x16x32_bf16(
                        ahi[mt], bfr[nt], acc[mt][nt], 0, 0, 0);
                    acc[mt][nt] = __builtin_amdgcn_mfma_f32_16x16x32_bf16(
                        alo[mt], bfr[nt], acc[mt][nt], 0, 0, 0);
                }
        }
        __builtin_amdgcn_s_setprio(0);
    }
}

// ---------------------------------------------------------------------------
// QKV projection. 1-D 256 blocks/z, XCD-chunked 4Mx8N supertile raster.
// ---------------------------------------------------------------------------
__global__ __launch_bounds__(256)
void qkv_mfma(const __bf16* __restrict__ Abf, const __bf16* __restrict__ Whi,
              const float* __restrict__ bq, const float* __restrict__ bk,
              const float* __restrict__ bv,
              __bf16* __restrict__ Qo, __bf16* __restrict__ Ko, __bf16* __restrict__ Vt)
{
    __shared__ __align__(16) char smem[65536];   // A dbuf 32K | W dbuf 32K

    const int z = blockIdx.y;
    const float* bias = (z == 0) ? bq : (z == 1) ? bk : bv;
    const float scale = (z == 0) ? 0.125f * LOG2E : 1.0f;
    const __bf16* A   = Abf + (size_t)z * BSc * Dc;
    const __bf16* Wh  = Whi + (size_t)z * Dc * Dc;

    const int lb  = (blockIdx.x & 7) * 32 + (blockIdx.x >> 3);
    const int idx = lb & 31;
    const int gm0 = ((lb >> 5) * 4 + (idx & 3)) * 128;
    const int gn0 = (idx >> 2) * 128;

    f32x4 acc[4][4];
#pragma unroll
    for (int mt = 0; mt < 4; ++mt)
#pragma unroll
        for (int nt = 0; nt < 4; ++nt) acc[mt][nt] = {0.f, 0.f, 0.f, 0.f};

    sweep128bb<Dc>(A, Wh, smem, smem + 32768, gm0, gn0, acc);

    const int tid = threadIdx.x;
    const int w = tid >> 6, lane = tid & 63;
    const int cc = lane & 15, g = lane >> 4;
    const int wm = (w & 1) * 64, wn = (w >> 1) * 64;

    float bias4[4];
#pragma unroll
    for (int nt = 0; nt < 4; ++nt) bias4[nt] = bias[gn0 + wn + nt * 16 + cc];

    if (z == 2) {
#pragma unroll
        for (int mt = 0; mt < 4; ++mt)
#pragma unroll
            for (int nt = 0; nt < 4; ++nt) {
                const int col = gn0 + wn + nt * 16 + cc;
                const int h = col >> 6, dh = col & 63;
                const int row0 = gm0 + wm + mt * 16 + g * 4;
                const int b = row0 >> 11, s0 = row0 & 2047;
                bf16x4 vv;
#pragma unroll
                for (int reg = 0; reg < 4; ++reg)
                    vv[reg] = (__bf16)(acc[mt][nt][reg] + bias4[nt]);
                *(bf16x4*)&Vt[(((size_t)(b * Hc + h)) * DHc + dh) * Sc + s0] = vv;
            }
    } else {
        __bf16* O = (z == 0) ? Qo : Ko;
#pragma unroll
        for (int mt = 0; mt < 4; ++mt)
#pragma unroll
            for (int nt = 0; nt < 4; ++nt) {
                const int col = gn0 + wn + nt * 16 + cc;
                const int h = col >> 6, dh = col & 63;
#pragma unroll
                for (int reg = 0; reg < 4; ++reg) {
                    const int row = gm0 + wm + mt * 16 + g * 4 + reg;
                    const int b = row >> 11, s = row & 2047;
                    O[(((size_t)(b * Hc + h)) * Sc + s) * DHc + dh] =
                        (__bf16)((acc[mt][nt][reg] + bias4[nt]) * scale);
                }
            }
    }
}

// ---------------------------------------------------------------------------
// Output projection: out = (ctxHi+ctxLo) @ Wo^T + bo, fp32 out.
// M64xN128 sweep64p; 1-D grid 512, XCD-chunked 8x8 supertile raster.
// ---------------------------------------------------------------------------
__global__ __launch_bounds__(256)
void out_mfma(const __bf16* __restrict__ ctxHi, const __bf16* __restrict__ ctxLo,
              const __bf16* __restrict__ Wohi,
              const float* __restrict__ bo, float* __restrict__ out)
{
    __shared__ __align__(16) char smem[65536];   // W dbuf 32K | Ahi 16K | Alo 16K

    const int lb = (blockIdx.x & 7) * 64 + (blockIdx.x >> 3);
    const int gm0 = ((lb >> 6) * 8 + (lb & 7)) * 64;
    const int gn0 = ((lb >> 3) & 7) * 128;

    f32x4 acc[2][4];
#pragma unroll
    for (int mt = 0; mt < 2; ++mt)
#pragma unroll
        for (int nt = 0; nt < 4; ++nt) acc[mt][nt] = {0.f, 0.f, 0.f, 0.f};

    sweep64p(ctxHi, ctxLo, Wohi, smem, smem + 32768, smem + 49152, gm0, gn0, acc);

    const int tid = threadIdx.x;
    const int w = tid >> 6, lane = tid & 63;
    const int cc = lane & 15, g = lane >> 4;
    const int wm = (w & 1) * 32, wn = (w >> 1) * 64;

    float bias4[4];
#pragma unroll
    for (int nt = 0; nt < 4; ++nt) bias4[nt] = bo[gn0 + wn + nt * 16 + cc];

#pragma unroll
    for (int mt = 0; mt < 2; ++mt)
#pragma unroll
        for (int nt = 0; nt < 4; ++nt) {
            const int col = gn0 + wn + nt * 16 + cc;
#pragma unroll
            for (int reg = 0; reg < 4; ++reg) {
                const int row = gm0 + wm + mt * 16 + g * 4 + reg;
                out[(size_t)row * Dc + col] = acc[mt][nt][reg] + bias4[nt];
            }
        }
}

// ---------------------------------------------------------------------------
// attn helpers. LDS key(row) = (row&7)^((row>>3)&7) (conflict-free, R23).
// ---------------------------------------------------------------------------
__device__ __forceinline__ void stage_pair(const __bf16* Kb, const __bf16* Vtb,
                                           char* H, int t0,
                                           int rowi0, int ski0, int ci0,
                                           int rowi1, int ski1, int ci1)
{
#pragma unroll
    for (int s = 0; s < 2; ++s) {
        char* B = H + s * 16384;
        const int kn = (t0 + s) * 64;
        GLDS16(Kb + (size_t)(kn + rowi0) * DHc + ski0 * 8, B + ci0 * 16);
        GLDS16(Vtb + (size_t)rowi0 * Sc + kn + ski0 * 8, B + 8192 + ci0 * 16);
        GLDS16(Kb + (size_t)(kn + rowi1) * DHc + ski1 * 8, B + ci1 * 16);
        GLDS16(Vtb + (size_t)rowi1 * Sc + kn + ski1 * 8, B + 8192 + ci1 * 16);
    }
}

__device__ __forceinline__ void qk_tile(const char* Ks, const bf16x8 qa[4],
                                        const f32x16& zb, int c, int u,
                                        f32x16& s0, f32x16& s1)
{
#pragma unroll
    for (int nt = 0; nt < 2; ++nt) {
        const int row = nt * 32 + c;
        const int rx  = (((row & 7) ^ ((row >> 3) & 7)) << 4);
        const bf16x8 kb0 = *(const bf16x8*)(Ks + row * 128 + ((u * 16) ^ rx));
        f32x16 z = __builtin_amdgcn_mfma_f32_32x32x16_bf16(kb0, qa[0], zb, 0, 0, 0);
#pragma unroll
        for (int ch = 1; ch < 4; ++ch) {
            const bf16x8 kb = *(const bf16x8*)
                (Ks + row * 128 + ((ch * 32 + u * 16) ^ rx));
            z = __builtin_amdgcn_mfma_f32_32x32x16_bf16(kb, qa[ch], z, 0, 0, 0);
        }
        if (nt == 0) s0 = z; else s1 = z;
    }
}

// one softmax chunk (4 scores): chunk = nt*4+rr, compile-time.
__device__ __forceinline__ void sm_chunk(int chunk,
                                         const f32x16& s0, const f32x16& s1,
                                         unsigned long long mw, int u,
                                         float lp[4], unsigned pk[8][2])
{
    const int nt = chunk >> 2, rr = chunk & 3;
    const unsigned nib = (unsigned)(mw >> (nt * 32 + rr * 8 + u * 4)) & 0xFu;
    float pv[4];
#pragma unroll
    for (int r = 0; r < 4; ++r) {
        float p = __builtin_amdgcn_exp2f((nt == 0) ? s0[rr * 4 + r]
                                                   : s1[rr * 4 + r]);
        p = (nib & (1u << r)) ? 0.f : p;
        lp[rr] += p;
        pv[r] = p;
    }
    bf16x2 t0; t0[0] = (__bf16)pv[0]; t0[1] = (__bf16)pv[1];
    bf16x2 t1; t1[0] = (__bf16)pv[2]; t1[1] = (__bf16)pv[3];
    pk[chunk][0] = __builtin_bit_cast(unsigned, t0);
    pk[chunk][1] = __builtin_bit_cast(unsigned, t1);
}

__device__ __forceinline__ void redist(const unsigned pk[8][2], bf16x8 pa[4])
{
#pragma unroll
    for (int kc = 0; kc < 4; ++kc) {
        const int c0 = (kc >> 1) * 4 + (kc & 1) * 2;
        uint32x2 w0 = __builtin_amdgcn_permlane32_swap(
            pk[c0][0], pk[c0 + 1][0], false, false);
        uint32x2 w1 = __builtin_amdgcn_permlane32_swap(
            pk[c0][1], pk[c0 + 1][1], false, false);
        uint32x4 wds;
        wds[0] = w0[0]; wds[1] = w1[0]; wds[2] = w0[1]; wds[3] = w1[1];
        pa[kc] = __builtin_bit_cast(bf16x8, wds);
    }
}

// ---------------------------------------------------------------------------
// Flash attention: 4 waves x 32 q = 128 q/block, grid 512 (2 blocks/CU),
// XCD-grouped raster (chunk of 64 blocks owns 4 bhs; K/V 2MB L2-resident).
// 2 KV-tiles/barrier, 64KB LDS. Span schedule: QK0 -> QK1 -> SM0 ->
// [PV0 || SM1 interleaved 1:1] -> PV1.
// ---------------------------------------------------------------------------
__global__ __launch_bounds__(256, 2)
void attn_mfma(const __bf16* __restrict__ Q, const __bf16* __restrict__ K,
               const __bf16* __restrict__ Vt,
               const unsigned long long* __restrict__ mp,
               __bf16* __restrict__ ctxHi, __bf16* __restrict__ ctxLo)
{
    __shared__ __align__(16) char smem[65536];

    const int tid  = threadIdx.x;
    const int w    = tid >> 6;
    const int lane = tid & 63;
    const int c    = lane & 31;
    const int u    = lane >> 5;

    const int bx  = blockIdx.x;
    const int lb  = (bx & 7) * 64 + (bx >> 3);
    const int bh  = lb >> 4;
    const int qb  = lb & 15;
    const int b   = bh >> 4;
    const int h   = bh & 15;
    const int qw  = qb * 128 + w * 32;

    const __bf16* Qb  = Q  + (size_t)bh * Sc * DHc;
    const __bf16* Kb  = K  + (size_t)bh * Sc * DHc;
    const __bf16* Vtb = Vt + (size_t)bh * DHc * Sc;

    bf16x8 qa[4];
#pragma unroll
    for (int ch = 0; ch < 4; ++ch)
        qa[ch] = *(const bf16x8*)&Qb[(size_t)(qw + c) * DHc + ch * 16 + u * 8];

    f32x16 o[2], zb;
#pragma unroll
    for (int i = 0; i < 16; ++i) { o[0][i] = 0.f; o[1][i] = 0.f; zb[i] = -24.f; }
    float lp[4] = {0.f, 0.f, 0.f, 0.f};

    const int ci0 = tid,        ci1 = 256 + tid;
    const int rowi0 = ci0 >> 3, rowi1 = ci1 >> 3;
    const int ski0 = (ci0 & 7) ^ (rowi0 & 7) ^ ((rowi0 >> 3) & 7);
    const int ski1 = (ci1 & 7) ^ (rowi1 & 7) ^ ((rowi1 >> 3) & 7);

    const size_t mbase = ((size_t)(b * Sc + qw + c) << 5);

    // prologue: tiles 0,1 into half 0
    stage_pair(Kb, Vtb, smem, 0, rowi0, ski0, ci0, rowi1, ski1, ci1);

    for (int j = 0; j < 16; ++j) {
        __syncthreads();    // drains pair staged last span
        if (j + 1 < 16)
            stage_pair(Kb, Vtb, smem + ((j + 1) & 1) * 32768, 2 * j + 2,
                       rowi0, ski0, ci0, rowi1, ski1, ci1);

        const char* H = smem + (j & 1) * 32768;
        const unsigned long long mw0 = mp[mbase + 2 * j];
        const unsigned long long mw1 = mp[mbase + 2 * j + 1];

        // ---- QK both tiles (back-to-back MFMA clusters) ----
        f32x16 a0, a1, b0, b1;
        __builtin_amdgcn_s_setprio(1);
        qk_tile(H,         qa, zb, c, u, a0, a1);
        qk_tile(H + 16384, qa, zb, c, u, b0, b1);
        __builtin_amdgcn_s_setprio(0);

        // ---- SM0 (executes in QK1's MFMA shadow) ----
        unsigned pk0[8][2];
#pragma unroll
        for (int chk = 0; chk < 8; ++chk)
            sm_chunk(chk, a0, a1, mw0, u, lp, pk0);
        bf16x8 pa0[4];
        redist(pk0, pa0);

        // ---- PV0 with SM1 interleaved 1:1 ----
        unsigned pk1[8][2];
        const char* Vs0 = H + 8192;
        __builtin_amdgcn_s_setprio(1);
#pragma unroll
        for (int dt = 0; dt < 2; ++dt) {
            const int row = dt * 32 + c;
            const int rx  = (((row & 7) ^ ((row >> 3) & 7)) << 4);
#pragma unroll
            for (int kc = 0; kc < 4; ++kc) {
                const bf16x8 vb = *(const bf16x8*)
                    (Vs0 + row * 128 + ((kc * 32 + u * 16) ^ rx));
                o[dt] = __builtin_amdgcn_mfma_f32_32x32x16_bf16(pa0[kc], vb, o[dt], 0, 0, 0);
                sm_chunk(dt * 4 + kc, b0, b1, mw1, u, lp, pk1);
            }
        }
        __builtin_amdgcn_s_setprio(0);

        bf16x8 pa1[4];
        redist(pk1, pa1);

        // ---- PV1 ----
        const char* Vs1 = H + 24576;
        __builtin_amdgcn_s_setprio(1);
#pragma unroll
        for (int dt = 0; dt < 2; ++dt) {
            const int row = dt * 32 + c;
            const int rx  = (((row & 7) ^ ((row >> 3) & 7)) << 4);
#pragma unroll
            for (int kc = 0; kc < 4; ++kc) {
                const bf16x8 vb = *(const bf16x8*)
                    (Vs1 + row * 128 + ((kc * 32 + u * 16) ^ rx));
                o[dt] = __builtin_amdgcn_mfma_f32_32x32x16_bf16(pa1[kc], vb, o[dt], 0, 0, 0);
            }
        }
        __builtin_amdgcn_s_setprio(0);
    }

    // ---- epilogue ----
    float lsum = (lp[0] + lp[1]) + (lp[2] + lp[3]);
    lsum += __shfl_xor(lsum, 32);
    const float linv = 1.0f / lsum;

    float inv[16];
#pragma unroll
    for (int i = 0; i < 16; ++i)
        inv[i] = __shfl(linv, (i & 3) + 8 * (i >> 2) + 4 * u);

#pragma unroll
    for (int dt = 0; dt < 2; ++dt)
#pragma unroll
        for (int i = 0; i < 16; ++i) {
            const int q = qw + (i & 3) + 8 * (i >> 2) + 4 * u;
            const size_t idx = ((size_t)b * Sc + q) * Dc + h * 64 + dt * 32 + c;
            const float v = o[dt][i] * inv[i];
            const __bf16 hi = (__bf16)v;
            ctxHi[idx] = hi;
            ctxLo[idx] = (__bf16)(v - (float)hi);
        }
}

extern "C" void kernel_launch(void* const* d_in, const int* in_sizes, int n_in,
                              void* d_out, int out_size, void* d_ws, size_t ws_size,
                              hipStream_t stream)
{
    const float* key   = (const float*)d_in[0];
    const float* value = (const float*)d_in[1];
    const float* query = (const float*)d_in[2];
    const int*   mask  = (const int*)  d_in[3];
    const float* Wq    = (const float*)d_in[4];
    const float* bq    = (const float*)d_in[5];
    const float* Wk    = (const float*)d_in[6];
    const float* bk    = (const float*)d_in[7];
    const float* Wv    = (const float*)d_in[8];
    const float* bv    = (const float*)d_in[9];
    const float* Wo    = (const float*)d_in[10];
    const float* bo    = (const float*)d_in[11];
    float* out = (float*)d_out;

    char* wsb = (char*)d_ws;
    __bf16* Qbf  = (__bf16*)(wsb);                                 // 8 MB
    __bf16* Kbf  = (__bf16*)(wsb + ((size_t)8  << 20));            // 8 MB
    __bf16* Vt   = (__bf16*)(wsb + ((size_t)16 << 20));            // 8 MB
    unsigned long long* mpk = (unsigned long long*)(wsb + ((size_t)32 << 20)); // 1 MB
    __bf16* Whi  = (__bf16*)(wsb + ((size_t)33 << 20));            // 8 MB (Wq,Wk,Wv,Wo)
    __bf16* ctxHi = (__bf16*)(wsb + ((size_t)41 << 20));           // 8 MB
    __bf16* ctxLo = (__bf16*)(wsb + ((size_t)49 << 20));           // 8 MB
    __bf16* Abf  = (__bf16*)(wsb + ((size_t)57 << 20));            // 24 MB

    prep<<<dim3(18432), 256, 0, stream>>>(Wq, Wk, Wv, Wo, Whi,
                                          query, key, value, Abf,
                                          mask, mpk);

    dim3 gqkv(256, 3);
    qkv_mfma<<<gqkv, 256, 0, stream>>>(Abf, Whi, bq, bk, bv, Qbf, Kbf, Vt);

    attn_mfma<<<dim3(512), 256, 0, stream>>>(Qbf, Kbf, Vt, mpk, ctxHi, ctxLo);

    out_mfma<<<dim3(512), 256, 0, stream>>>(ctxHi, ctxLo, Whi + (size_t)3 * Dc * Dc,
                                            bo, out);
}

// Round 15
// 244.347 us; speedup vs baseline: 1.0294x; 1.0294x over previous
//
#include <hip/hip_runtime.h>
#include <math.h>

// MultiHeadedAttention  B=2, S=2048, D=1024, H=16, DH=64 (fp32 in/out)
// R25 (baseline = R24: attn 57.6us): complete the interleave symmetrically.
// Span schedule: QK0 -> [QK1 || SM0 1:1] -> redist0 -> [PV0 || SM1 1:1]
// -> redist1 -> PV1 (+ next-span mask prefetch). Same math/fp order as R24;
// only issue order changes (fills QK1's dependent-chain stalls with SM0
// VALU, mirroring the proven PV0||SM1 win). Everything else identical.
// ws: Qbf@0 Kbf@8M Vt@16M mpk@32M Whi@33M ctxHi@41M ctxLo@49M Abf@57M

constexpr int Bc  = 2;
constexpr int Sc  = 2048;
constexpr int Dc  = 1024;
constexpr int Hc  = 16;
constexpr int DHc = 64;
constexpr int BSc = Bc * Sc;     // 4096

constexpr float LOG2E = 1.4426950408889634f;

typedef __bf16 bf16x8 __attribute__((ext_vector_type(8)));
typedef __bf16 bf16x4 __attribute__((ext_vector_type(4)));
typedef __bf16 bf16x2 __attribute__((ext_vector_type(2)));
typedef float  f32x4  __attribute__((ext_vector_type(4)));
typedef float  f32x16 __attribute__((ext_vector_type(16)));
typedef unsigned uint32x2 __attribute__((ext_vector_type(2)));
typedef unsigned uint32x4 __attribute__((ext_vector_type(4)));

#define GLDS16(gp, lp) __builtin_amdgcn_global_load_lds( \
    (const __attribute__((address_space(1))) void*)(gp), \
    (__attribute__((address_space(3))) void*)(lp), 16, 0, 0)

// ---------------------------------------------------------------------------
// prep: fused wsplit (blocks 0..4095) + acast (4096..10239) +
// mask_pack (10240..18431). No inter-part dependencies.
// ---------------------------------------------------------------------------
__global__ __launch_bounds__(256)
void prep(const float* __restrict__ W0, const float* __restrict__ W1,
          const float* __restrict__ W2, const float* __restrict__ W3,
          __bf16* __restrict__ Whi,
          const float* __restrict__ A0, const float* __restrict__ A1,
          const float* __restrict__ A2, __bf16* __restrict__ Abf,
          const int* __restrict__ mask, unsigned long long* __restrict__ mpk)
{
    const int bid = blockIdx.x;
    const int tid = threadIdx.x;

    if (bid < 4096) {
        const float* src[4] = {W0, W1, W2, W3};
        const int z  = bid >> 10;
        const int bx = bid & 1023;
        const size_t idx = ((size_t)bx * 256 + tid) * 4;
        const float4 v = *(const float4*)&src[z][idx];
        bf16x4 o;
        o[0] = (__bf16)v.x; o[1] = (__bf16)v.y;
        o[2] = (__bf16)v.z; o[3] = (__bf16)v.w;
        *(bf16x4*)&Whi[(size_t)z * Dc * Dc + idx] = o;
    } else if (bid < 10240) {
        const float* src[3] = {A0, A1, A2};
        const int lin = bid - 4096;
        const int z  = lin >> 11;
        const int bx = lin & 2047;
        const size_t idx = ((size_t)bx * 256 + tid) * 8;
        const float4 a = *(const float4*)&src[z][idx];
        const float4 b = *(const float4*)&src[z][idx + 4];
        bf16x8 o;
        o[0] = (__bf16)a.x; o[1] = (__bf16)a.y; o[2] = (__bf16)a.z; o[3] = (__bf16)a.w;
        o[4] = (__bf16)b.x; o[5] = (__bf16)b.y; o[6] = (__bf16)b.z; o[7] = (__bf16)b.w;
        *(bf16x8*)&Abf[(size_t)z * BSc * Dc + idx] = o;
    } else {
        const int bx   = bid - 10240;
        const int lane = tid & 63;
        const size_t waveBase = ((size_t)bx * 4 + (tid >> 6)) * 256;
        unsigned long long b0 = __ballot(mask[waveBase + lane]        != 0);
        unsigned long long b1 = __ballot(mask[waveBase + 64 + lane]   != 0);
        unsigned long long b2 = __ballot(mask[waveBase + 128 + lane]  != 0);
        unsigned long long b3 = __ballot(mask[waveBase + 192 + lane]  != 0);
        if (lane == 0) {
            unsigned long long* dst = mpk + (waveBase >> 6);
            dst[0] = b0; dst[1] = b1; dst[2] = b2; dst[3] = b3;
        }
    }
}

// ---------------------------------------------------------------------------
// Pure double-GLDS K-sweep, M-tile 128 (qkv).
// ---------------------------------------------------------------------------
template<int KD>
__device__ __forceinline__ void sweep128bb(const __bf16* __restrict__ A,
                                           const __bf16* __restrict__ Wh,
                                           char* AsB, char* WsB,
                                           int gm0, int gn0, f32x4 acc[4][4])
{
    const int tid  = threadIdx.x;
    const int w    = tid >> 6;
    const int lane = tid & 63;
    const int cc   = lane & 15;
    const int g    = lane >> 4;
    const int wm   = (w & 1) * 64;
    const int wn   = (w >> 1) * 64;

    int wrow[4], wchk[4];
#pragma unroll
    for (int r = 0; r < 4; ++r) {
        const int L = r * 256 + tid;
        wrow[r] = L >> 3;
        wchk[r] = (L & 7) ^ (wrow[r] & 7);
    }

#pragma unroll
    for (int r = 0; r < 4; ++r) {
        GLDS16(Wh + (size_t)(gn0 + wrow[r]) * KD + wchk[r] * 8,
               WsB + (r * 256 + tid) * 16);
        GLDS16(A + (size_t)(gm0 + wrow[r]) * KD + wchk[r] * 8,
               AsB + (r * 256 + tid) * 16);
    }

    for (int it = 0; it < KD / 64; ++it) {
        const char* As = AsB + (it & 1) * 16384;
        const char* Ws = WsB + (it & 1) * 16384;
        __syncthreads();

        if (it + 1 < KD / 64) {
            const int kn = (it + 1) * 64;
            char* Wn = WsB + ((it + 1) & 1) * 16384;
            char* An = AsB + ((it + 1) & 1) * 16384;
#pragma unroll
            for (int r = 0; r < 4; ++r) {
                GLDS16(Wh + (size_t)(gn0 + wrow[r]) * KD + kn + wchk[r] * 8,
                       Wn + (r * 256 + tid) * 16);
                GLDS16(A + (size_t)(gm0 + wrow[r]) * KD + kn + wchk[r] * 8,
                       An + (r * 256 + tid) * 16);
            }
        }

        __builtin_amdgcn_s_setprio(1);
#pragma unroll
        for (int kk = 0; kk < 2; ++kk) {
            const int cb4 = (kk * 4 + g) << 4;
            bf16x8 af[4], bfr[4];
#pragma unroll
            for (int mt = 0; mt < 4; ++mt) {
                const int row = wm + mt * 16 + cc;
                af[mt] = *(const bf16x8*)(As + row * 128 + (cb4 ^ ((row & 7) << 4)));
            }
#pragma unroll
            for (int nt = 0; nt < 4; ++nt) {
                const int row = wn + nt * 16 + cc;
                bfr[nt] = *(const bf16x8*)(Ws + row * 128 + (cb4 ^ ((row & 7) << 4)));
            }
#pragma unroll
            for (int mt = 0; mt < 4; ++mt)
#pragma unroll
                for (int nt = 0; nt < 4; ++nt)
                    acc[mt][nt] = __builtin_amdgcn_mfma_f32_16x16x32_bf16(
                        af[mt], bfr[nt], acc[mt][nt], 0, 0, 0);
        }
        __builtin_amdgcn_s_setprio(0);
    }
}

// ---------------------------------------------------------------------------
// Pipelined hi/lo K-sweep, M64 (out projection).
// ---------------------------------------------------------------------------
__device__ __forceinline__ void sweep64p(const __bf16* __restrict__ Ahi,
                                         const __bf16* __restrict__ Alo,
                                         const __bf16* __restrict__ Wh,
                                         char* WsB, char* AhB, char* AlB,
                                         int gm0, int gn0, f32x4 acc[2][4])
{
    const int tid  = threadIdx.x;
    const int w    = tid >> 6;
    const int lane = tid & 63;
    const int cc   = lane & 15;
    const int g    = lane >> 4;
    const int wm   = (w & 1) * 32;
    const int wn   = (w >> 1) * 64;

    int wrow[4], wchk[4];
#pragma unroll
    for (int r = 0; r < 4; ++r) {
        const int L = r * 256 + tid;
        wrow[r] = L >> 3;
        wchk[r] = (L & 7) ^ (wrow[r] & 7);
    }
    int arow[2], achk[2];
#pragma unroll
    for (int r = 0; r < 2; ++r) {
        const int L = r * 256 + tid;
        arow[r] = L >> 3;
        achk[r] = (L & 7) ^ (arow[r] & 7);
    }

#pragma unroll
    for (int r = 0; r < 4; ++r)
        GLDS16(Wh + (size_t)(gn0 + wrow[r]) * Dc + wchk[r] * 8,
               WsB + (r * 256 + tid) * 16);
#pragma unroll
    for (int r = 0; r < 2; ++r) {
        GLDS16(Ahi + (size_t)(gm0 + arow[r]) * Dc + achk[r] * 8,
               AhB + (r * 256 + tid) * 16);
        GLDS16(Alo + (size_t)(gm0 + arow[r]) * Dc + achk[r] * 8,
               AlB + (r * 256 + tid) * 16);
    }

    for (int it = 0; it < Dc / 64; ++it) {
        const char* Ws = WsB + (it & 1) * 16384;
        const char* Ah = AhB + (it & 1) * 8192;
        const char* Al = AlB + (it & 1) * 8192;
        __syncthreads();

        if (it + 1 < Dc / 64) {
            const int kn = (it + 1) * 64;
            char* Wn = WsB + ((it + 1) & 1) * 16384;
            char* Hn = AhB + ((it + 1) & 1) * 8192;
            char* Ln = AlB + ((it + 1) & 1) * 8192;
#pragma unroll
            for (int r = 0; r < 4; ++r)
                GLDS16(Wh + (size_t)(gn0 + wrow[r]) * Dc + kn + wchk[r] * 8,
                       Wn + (r * 256 + tid) * 16);
#pragma unroll
            for (int r = 0; r < 2; ++r) {
                GLDS16(Ahi + (size_t)(gm0 + arow[r]) * Dc + kn + achk[r] * 8,
                       Hn + (r * 256 + tid) * 16);
                GLDS16(Alo + (size_t)(gm0 + arow[r]) * Dc + kn + achk[r] * 8,
                       Ln + (r * 256 + tid) * 16);
            }
        }

        __builtin_amdgcn_s_setprio(1);
#pragma unroll
        for (int kk = 0; kk < 2; ++kk) {
            const int cb4 = (kk * 4 + g) << 4;
            bf16x8 ahi[2], alo[2], bfr[4];
#pragma unroll
            for (int mt = 0; mt < 2; ++mt) {
                const int row = wm + mt * 16 + cc;
                const int off = row * 128 + (cb4 ^ ((row & 7) << 4));
                ahi[mt] = *(const bf16x8*)(Ah + off);
                alo[mt] = *(const bf16x8*)(Al + off);
            }
#pragma unroll
            for (int nt = 0; nt < 4; ++nt) {
                const int row = wn + nt * 16 + cc;
                bfr[nt] = *(const bf16x8*)(Ws + row * 128 + (cb4 ^ ((row & 7) << 4)));
            }
#pragma unroll
            for (int mt = 0; mt < 2; ++mt)
#pragma unroll
                for (int nt = 0; nt < 4; ++nt) {
                    acc[mt][nt] = __builtin_amdgcn_mfma_f32_16x16x32_bf16(
                        ahi[mt], bfr[nt], acc[mt][nt], 0, 0, 0);
                    acc[mt][nt] = __builtin_amdgcn_mfma_f32_16x16x32_bf16(
                        alo[mt], bfr[nt], acc[mt][nt], 0, 0, 0);
                }
        }
        __builtin_amdgcn_s_setprio(0);
    }
}

// ---------------------------------------------------------------------------
// QKV projection. 1-D 256 blocks/z, XCD-chunked 4Mx8N supertile raster.
// ---------------------------------------------------------------------------
__global__ __launch_bounds__(256)
void qkv_mfma(const __bf16* __restrict__ Abf, const __bf16* __restrict__ Whi,
              const float* __restrict__ bq, const float* __restrict__ bk,
              const float* __restrict__ bv,
              __bf16* __restrict__ Qo, __bf16* __restrict__ Ko, __bf16* __restrict__ Vt)
{
    __shared__ __align__(16) char smem[65536];   // A dbuf 32K | W dbuf 32K

    const int z = blockIdx.y;
    const float* bias = (z == 0) ? bq : (z == 1) ? bk : bv;
    const float scale = (z == 0) ? 0.125f * LOG2E : 1.0f;
    const __bf16* A   = Abf + (size_t)z * BSc * Dc;
    const __bf16* Wh  = Whi + (size_t)z * Dc * Dc;

    const int lb  = (blockIdx.x & 7) * 32 + (blockIdx.x >> 3);
    const int idx = lb & 31;
    const int gm0 = ((lb >> 5) * 4 + (idx & 3)) * 128;
    const int gn0 = (idx >> 2) * 128;

    f32x4 acc[4][4];
#pragma unroll
    for (int mt = 0; mt < 4; ++mt)
#pragma unroll
        for (int nt = 0; nt < 4; ++nt) acc[mt][nt] = {0.f, 0.f, 0.f, 0.f};

    sweep128bb<Dc>(A, Wh, smem, smem + 32768, gm0, gn0, acc);

    const int tid = threadIdx.x;
    const int w = tid >> 6, lane = tid & 63;
    const int cc = lane & 15, g = lane >> 4;
    const int wm = (w & 1) * 64, wn = (w >> 1) * 64;

    float bias4[4];
#pragma unroll
    for (int nt = 0; nt < 4; ++nt) bias4[nt] = bias[gn0 + wn + nt * 16 + cc];

    if (z == 2) {
#pragma unroll
        for (int mt = 0; mt < 4; ++mt)
#pragma unroll
            for (int nt = 0; nt < 4; ++nt) {
                const int col = gn0 + wn + nt * 16 + cc;
                const int h = col >> 6, dh = col & 63;
                const int row0 = gm0 + wm + mt * 16 + g * 4;
                const int b = row0 >> 11, s0 = row0 & 2047;
                bf16x4 vv;
#pragma unroll
                for (int reg = 0; reg < 4; ++reg)
                    vv[reg] = (__bf16)(acc[mt][nt][reg] + bias4[nt]);
                *(bf16x4*)&Vt[(((size_t)(b * Hc + h)) * DHc + dh) * Sc + s0] = vv;
            }
    } else {
        __bf16* O = (z == 0) ? Qo : Ko;
#pragma unroll
        for (int mt = 0; mt < 4; ++mt)
#pragma unroll
            for (int nt = 0; nt < 4; ++nt) {
                const int col = gn0 + wn + nt * 16 + cc;
                const int h = col >> 6, dh = col & 63;
#pragma unroll
                for (int reg = 0; reg < 4; ++reg) {
                    const int row = gm0 + wm + mt * 16 + g * 4 + reg;
                    const int b = row >> 11, s = row & 2047;
                    O[(((size_t)(b * Hc + h)) * Sc + s) * DHc + dh] =
                        (__bf16)((acc[mt][nt][reg] + bias4[nt]) * scale);
                }
            }
    }
}

// ---------------------------------------------------------------------------
// Output projection: out = (ctxHi+ctxLo) @ Wo^T + bo, fp32 out.
// M64xN128 sweep64p; 1-D grid 512, XCD-chunked 8x8 supertile raster.
// ---------------------------------------------------------------------------
__global__ __launch_bounds__(256)
void out_mfma(const __bf16* __restrict__ ctxHi, const __bf16* __restrict__ ctxLo,
              const __bf16* __restrict__ Wohi,
              const float* __restrict__ bo, float* __restrict__ out)
{
    __shared__ __align__(16) char smem[65536];   // W dbuf 32K | Ahi 16K | Alo 16K

    const int lb = (blockIdx.x & 7) * 64 + (blockIdx.x >> 3);
    const int gm0 = ((lb >> 6) * 8 + (lb & 7)) * 64;
    const int gn0 = ((lb >> 3) & 7) * 128;

    f32x4 acc[2][4];
#pragma unroll
    for (int mt = 0; mt < 2; ++mt)
#pragma unroll
        for (int nt = 0; nt < 4; ++nt) acc[mt][nt] = {0.f, 0.f, 0.f, 0.f};

    sweep64p(ctxHi, ctxLo, Wohi, smem, smem + 32768, smem + 49152, gm0, gn0, acc);

    const int tid = threadIdx.x;
    const int w = tid >> 6, lane = tid & 63;
    const int cc = lane & 15, g = lane >> 4;
    const int wm = (w & 1) * 32, wn = (w >> 1) * 64;

    float bias4[4];
#pragma unroll
    for (int nt = 0; nt < 4; ++nt) bias4[nt] = bo[gn0 + wn + nt * 16 + cc];

#pragma unroll
    for (int mt = 0; mt < 2; ++mt)
#pragma unroll
        for (int nt = 0; nt < 4; ++nt) {
            const int col = gn0 + wn + nt * 16 + cc;
#pragma unroll
            for (int reg = 0; reg < 4; ++reg) {
                const int row = gm0 + wm + mt * 16 + g * 4 + reg;
                out[(size_t)row * Dc + col] = acc[mt][nt][reg] + bias4[nt];
            }
        }
}

// ---------------------------------------------------------------------------
// attn helpers. LDS key(row) = (row&7)^((row>>3)&7) (conflict-free, R23).
// ---------------------------------------------------------------------------
__device__ __forceinline__ void stage_pair(const __bf16* Kb, const __bf16* Vtb,
                                           char* H, int t0,
                                           int rowi0, int ski0, int ci0,
                                           int rowi1, int ski1, int ci1)
{
#pragma unroll
    for (int s = 0; s < 2; ++s) {
        char* B = H + s * 16384;
        const int kn = (t0 + s) * 64;
        GLDS16(Kb + (size_t)(kn + rowi0) * DHc + ski0 * 8, B + ci0 * 16);
        GLDS16(Vtb + (size_t)rowi0 * Sc + kn + ski0 * 8, B + 8192 + ci0 * 16);
        GLDS16(Kb + (size_t)(kn + rowi1) * DHc + ski1 * 8, B + ci1 * 16);
        GLDS16(Vtb + (size_t)rowi1 * Sc + kn + ski1 * 8, B + 8192 + ci1 * 16);
    }
}

// one softmax chunk (4 scores): chunk = nt*4+rr, compile-time.
__device__ __forceinline__ void sm_chunk(int chunk,
                                         const f32x16& s0, const f32x16& s1,
                                         unsigned long long mw, int u,
                                         float lp[4], unsigned pk[8][2])
{
    const int nt = chunk >> 2, rr = chunk & 3;
    const unsigned nib = (unsigned)(mw >> (nt * 32 + rr * 8 + u * 4)) & 0xFu;
    float pv[4];
#pragma unroll
    for (int r = 0; r < 4; ++r) {
        float p = __builtin_amdgcn_exp2f((nt == 0) ? s0[rr * 4 + r]
                                                   : s1[rr * 4 + r]);
        p = (nib & (1u << r)) ? 0.f : p;
        lp[rr] += p;
        pv[r] = p;
    }
    bf16x2 t0; t0[0] = (__bf16)pv[0]; t0[1] = (__bf16)pv[1];
    bf16x2 t1; t1[0] = (__bf16)pv[2]; t1[1] = (__bf16)pv[3];
    pk[chunk][0] = __builtin_bit_cast(unsigned, t0);
    pk[chunk][1] = __builtin_bit_cast(unsigned, t1);
}

__device__ __forceinline__ void redist(const unsigned pk[8][2], bf16x8 pa[4])
{
#pragma unroll
    for (int kc = 0; kc < 4; ++kc) {
        const int c0 = (kc >> 1) * 4 + (kc & 1) * 2;
        uint32x2 w0 = __builtin_amdgcn_permlane32_swap(
            pk[c0][0], pk[c0 + 1][0], false, false);
        uint32x2 w1 = __builtin_amdgcn_permlane32_swap(
            pk[c0][1], pk[c0 + 1][1], false, false);
        uint32x4 wds;
        wds[0] = w0[0]; wds[1] = w1[0]; wds[2] = w0[1]; wds[3] = w1[1];
        pa[kc] = __builtin_bit_cast(bf16x8, wds);
    }
}

// ---------------------------------------------------------------------------
// Flash attention: 4 waves x 32 q = 128 q/block, grid 512 (2 blocks/CU),
// XCD-grouped raster (chunk of 64 blocks owns 4 bhs; K/V 2MB L2-resident).
// 2 KV-tiles/barrier, 64KB LDS. Span: QK0 -> [QK1||SM0] -> redist0 ->
// [PV0||SM1] -> redist1 -> PV1 (+ mask prefetch).
// ---------------------------------------------------------------------------
__global__ __launch_bounds__(256, 2)
void attn_mfma(const __bf16* __restrict__ Q, const __bf16* __restrict__ K,
               const __bf16* __restrict__ Vt,
               const unsigned long long* __restrict__ mp,
               __bf16* __restrict__ ctxHi, __bf16* __restrict__ ctxLo)
{
    __shared__ __align__(16) char smem[65536];

    const int tid  = threadIdx.x;
    const int w    = tid >> 6;
    const int lane = tid & 63;
    const int c    = lane & 31;
    const int u    = lane >> 5;

    const int bx  = blockIdx.x;
    const int lb  = (bx & 7) * 64 + (bx >> 3);
    const int bh  = lb >> 4;
    const int qb  = lb & 15;
    const int b   = bh >> 4;
    const int h   = bh & 15;
    const int qw  = qb * 128 + w * 32;

    const __bf16* Qb  = Q  + (size_t)bh * Sc * DHc;
    const __bf16* Kb  = K  + (size_t)bh * Sc * DHc;
    const __bf16* Vtb = Vt + (size_t)bh * DHc * Sc;

    bf16x8 qa[4];
#pragma unroll
    for (int ch = 0; ch < 4; ++ch)
        qa[ch] = *(const bf16x8*)&Qb[(size_t)(qw + c) * DHc + ch * 16 + u * 8];

    f32x16 o[2], zb;
#pragma unroll
    for (int i = 0; i < 16; ++i) { o[0][i] = 0.f; o[1][i] = 0.f; zb[i] = -24.f; }
    float lp[4] = {0.f, 0.f, 0.f, 0.f};

    const int ci0 = tid,        ci1 = 256 + tid;
    const int rowi0 = ci0 >> 3, rowi1 = ci1 >> 3;
    const int ski0 = (ci0 & 7) ^ (rowi0 & 7) ^ ((rowi0 >> 3) & 7);
    const int ski1 = (ci1 & 7) ^ (rowi1 & 7) ^ ((rowi1 >> 3) & 7);

    const size_t mbase = ((size_t)(b * Sc + qw + c) << 5);

    // prologue: tiles 0,1 into half 0; first mask pair
    stage_pair(Kb, Vtb, smem, 0, rowi0, ski0, ci0, rowi1, ski1, ci1);
    unsigned long long mw0 = mp[mbase + 0];
    unsigned long long mw1 = mp[mbase + 1];

    for (int j = 0; j < 16; ++j) {
        __syncthreads();    // drains pair staged last span
        if (j + 1 < 16)
            stage_pair(Kb, Vtb, smem + ((j + 1) & 1) * 32768, 2 * j + 2,
                       rowi0, ski0, ci0, rowi1, ski1, ci1);

        const char* H = smem + (j & 1) * 32768;

        // ---- QK0 ----
        f32x16 a0, a1, b0, b1;
        __builtin_amdgcn_s_setprio(1);
#pragma unroll
        for (int nt = 0; nt < 2; ++nt) {
            const int row = nt * 32 + c;
            const int rx  = (((row & 7) ^ ((row >> 3) & 7)) << 4);
            const bf16x8 kb0 = *(const bf16x8*)(H + row * 128 + ((u * 16) ^ rx));
            f32x16 z = __builtin_amdgcn_mfma_f32_32x32x16_bf16(kb0, qa[0], zb, 0, 0, 0);
#pragma unroll
            for (int ch = 1; ch < 4; ++ch) {
                const bf16x8 kb = *(const bf16x8*)
                    (H + row * 128 + ((ch * 32 + u * 16) ^ rx));
                z = __builtin_amdgcn_mfma_f32_32x32x16_bf16(kb, qa[ch], z, 0, 0, 0);
            }
            if (nt == 0) a0 = z; else a1 = z;
        }

        // ---- QK1 with SM0 interleaved 1:1 ----
        unsigned pk0[8][2];
        const char* K1 = H + 16384;
#pragma unroll
        for (int nt = 0; nt < 2; ++nt) {
            const int row = nt * 32 + c;
            const int rx  = (((row & 7) ^ ((row >> 3) & 7)) << 4);
            f32x16 z;
#pragma unroll
            for (int ch = 0; ch < 4; ++ch) {
                const bf16x8 kb = *(const bf16x8*)
                    (K1 + row * 128 + ((ch * 32 + u * 16) ^ rx));
                z = __builtin_amdgcn_mfma_f32_32x32x16_bf16(
                        kb, qa[ch], (ch == 0) ? zb : z, 0, 0, 0);
                sm_chunk(nt * 4 + ch, a0, a1, mw0, u, lp, pk0);
            }
            if (nt == 0) b0 = z; else b1 = z;
        }
        __builtin_amdgcn_s_setprio(0);

        bf16x8 pa0[4];
        redist(pk0, pa0);

        // ---- PV0 with SM1 interleaved 1:1 ----
        unsigned pk1[8][2];
        const char* Vs0 = H + 8192;
        __builtin_amdgcn_s_setprio(1);
#pragma unroll
        for (int dt = 0; dt < 2; ++dt) {
            const int row = dt * 32 + c;
            const int rx  = (((row & 7) ^ ((row >> 3) & 7)) << 4);
#pragma unroll
            for (int kc = 0; kc < 4; ++kc) {
                const bf16x8 vb = *(const bf16x8*)
                    (Vs0 + row * 128 + ((kc * 32 + u * 16) ^ rx));
                o[dt] = __builtin_amdgcn_mfma_f32_32x32x16_bf16(pa0[kc], vb, o[dt], 0, 0, 0);
                sm_chunk(dt * 4 + kc, b0, b1, mw1, u, lp, pk1);
            }
        }
        __builtin_amdgcn_s_setprio(0);

        bf16x8 pa1[4];
        redist(pk1, pa1);

        // ---- PV1 (+ next-span mask prefetch) ----
        if (j + 1 < 16) {
            mw0 = mp[mbase + 2 * j + 2];
            mw1 = mp[mbase + 2 * j + 3];
        }
        const char* Vs1 = H + 24576;
        __builtin_amdgcn_s_setprio(1);
#pragma unroll
        for (int dt = 0; dt < 2; ++dt) {
            const int row = dt * 32 + c;
            const int rx  = (((row & 7) ^ ((row >> 3) & 7)) << 4);
#pragma unroll
            for (int kc = 0; kc < 4; ++kc) {
                const bf16x8 vb = *(const bf16x8*)
                    (Vs1 + row * 128 + ((kc * 32 + u * 16) ^ rx));
                o[dt] = __builtin_amdgcn_mfma_f32_32x32x16_bf16(pa1[kc], vb, o[dt], 0, 0, 0);
            }
        }
        __builtin_amdgcn_s_setprio(0);
    }

    // ---- epilogue ----
    float lsum = (lp[0] + lp[1]) + (lp[2] + lp[3]);
    lsum += __shfl_xor(lsum, 32);
    const float linv = 1.0f / lsum;

    float inv[16];
#pragma unroll
    for (int i = 0; i < 16; ++i)
        inv[i] = __shfl(linv, (i & 3) + 8 * (i >> 2) + 4 * u);

#pragma unroll
    for (int dt = 0; dt < 2; ++dt)
#pragma unroll
        for (int i = 0; i < 16; ++i) {
            const int q = qw + (i & 3) + 8 * (i >> 2) + 4 * u;
            const size_t idx = ((size_t)b * Sc + q) * Dc + h * 64 + dt * 32 + c;
            const float v = o[dt][i] * inv[i];
            const __bf16 hi = (__bf16)v;
            ctxHi[idx] = hi;
            ctxLo[idx] = (__bf16)(v - (float)hi);
        }
}

extern "C" void kernel_launch(void* const* d_in, const int* in_sizes, int n_in,
                              void* d_out, int out_size, void* d_ws, size_t ws_size,
                              hipStream_t stream)
{
    const float* key   = (const float*)d_in[0];
    const float* value = (const float*)d_in[1];
    const float* query = (const float*)d_in[2];
    const int*   mask  = (const int*)  d_in[3];
    const float* Wq    = (const float*)d_in[4];
    const float* bq    = (const float*)d_in[5];
    const float* Wk    = (const float*)d_in[6];
    const float* bk    = (const float*)d_in[7];
    const float* Wv    = (const float*)d_in[8];
    const float* bv    = (const float*)d_in[9];
    const float* Wo    = (const float*)d_in[10];
    const float* bo    = (const float*)d_in[11];
    float* out = (float*)d_out;

    char* wsb = (char*)d_ws;
    __bf16* Qbf  = (__bf16*)(wsb);                                 // 8 MB
    __bf16* Kbf  = (__bf16*)(wsb + ((size_t)8  << 20));            // 8 MB
    __bf16* Vt   = (__bf16*)(wsb + ((size_t)16 << 20));            // 8 MB
    unsigned long long* mpk = (unsigned long long*)(wsb + ((size_t)32 << 20)); // 1 MB
    __bf16* Whi  = (__bf16*)(wsb + ((size_t)33 << 20));            // 8 MB (Wq,Wk,Wv,Wo)
    __bf16* ctxHi = (__bf16*)(wsb + ((size_t)41 << 20));           // 8 MB
    __bf16* ctxLo = (__bf16*)(wsb + ((size_t)49 << 20));           // 8 MB
    __bf16* Abf  = (__bf16*)(wsb + ((size_t)57 << 20));            // 24 MB

    prep<<<dim3(18432), 256, 0, stream>>>(Wq, Wk, Wv, Wo, Whi,
                                          query, key, value, Abf,
                                          mask, mpk);

    dim3 gqkv(256, 3);
    qkv_mfma<<<gqkv, 256, 0, stream>>>(Abf, Whi, bq, bk, bv, Qbf, Kbf, Vt);

    attn_mfma<<<dim3(512), 256, 0, stream>>>(Qbf, Kbf, Vt, mpk, ctxHi, ctxLo);

    out_mfma<<<dim3(512), 256, 0, stream>>>(ctxHi, ctxLo, Whi + (size_t)3 * Dc * Dc,
                                            bo, out);
}